// Round 1
// baseline (524.267 us; speedup 1.0000x reference)
//
#include <hip/hip_runtime.h>
#include <stdint.h>

#define HGT   24
#define WID   24
#define NHEAD 12
#define EMB   768
#define HD    64
#define NGRID 576
#define NTOK  577
#define BATCH 32
#define MROWS (BATCH * NTOK)   // 18464
#define NQT   10               // ceil(577/64) q-tiles
#define NKT   10               // ceil(577/64) kv-tiles

typedef __attribute__((ext_vector_type(8))) short bf16x8;
typedef __attribute__((ext_vector_type(4))) float f32x4;

__device__ __forceinline__ short f2bf(float f) {
    union { float f; unsigned u; } c; c.f = f;
    unsigned r = (c.u + 0x7FFFu + ((c.u >> 16) & 1u)) >> 16;
    return (short)(r & 0xFFFFu);
}

// ---------------------------------------------------------------- cast f32->bf16
__global__ void cast_f32_bf16(const float* __restrict__ src, short* __restrict__ dst, int n) {
    int i = (blockIdx.x * blockDim.x + threadIdx.x) * 4;
    int stride = gridDim.x * blockDim.x * 4;
    for (int j = i; j < n; j += stride) {
        float4 v = *(const float4*)(src + j);
        short4 o;
        o.x = f2bf(v.x); o.y = f2bf(v.y); o.z = f2bf(v.z); o.w = f2bf(v.w);
        *(short4*)(dst + j) = o;
    }
}

// ---------------------------------------------------------------- bias expand [H][576][576]
__global__ void bias_expand(const float* __restrict__ rel, float* __restrict__ be) {
    int i = blockIdx.x;     // query spatial 0..575
    int j = threadIdx.x;    // key spatial 0..575
    int y1 = i / WID, x1 = i % WID;
    int y2 = j / WID, x2 = j % WID;
    int idx = (y1 - y2 + HGT - 1) * (2 * WID - 1) + (x1 - x2 + WID - 1);
#pragma unroll
    for (int h = 0; h < NHEAD; h++)
        be[((size_t)h * NGRID + i) * NGRID + j] = rel[(size_t)idx * NHEAD + h];
}

// ---------------------------------------------------------------- GEMM  C = A @ B^T (+bias)
// A: [M][K]  (MODE 0: fp32 x;  MODE 1: bf16 attn_out)
// B: [Ncols][K] bf16 row-major (i.e. W as given)
// MODE 0: Ncols=2304 (Wq|Wk|Wv), writes bf16 into qkv[3][B][H][NTOK][HD], bias b0/b1/b2
// MODE 1: Ncols=768 (Wp), writes f32 into out[M][768] + b0
template <int MODE>
__global__ __launch_bounds__(256) void gemm_bt(
    const void* __restrict__ Aptr, const short* __restrict__ Bw,
    const float* __restrict__ b0, const float* __restrict__ b1, const float* __restrict__ b2,
    void* __restrict__ Outp, int M, int Ncols, int K)
{
    __shared__ __align__(16) short Asl[128][40];
    __shared__ __align__(16) short Bsl[128][40];

    const int t    = threadIdx.x;
    const int lane = t & 63;
    const int w    = t >> 6;
    const int wr   = (w >> 1) * 64;
    const int wc   = (w & 1) * 64;
    const int lg   = lane >> 4;   // 0..3
    const int li   = lane & 15;
    const int tm   = blockIdx.y * 128;
    const int tn   = blockIdx.x * 128;

    f32x4 acc[4][4];
#pragma unroll
    for (int i = 0; i < 4; i++)
#pragma unroll
        for (int j = 0; j < 4; j++) acc[i][j] = (f32x4){0.f, 0.f, 0.f, 0.f};

    const int srow0 = t >> 2;         // 0..63
    const int scol  = (t & 3) * 8;    // 0,8,16,24

    for (int k0 = 0; k0 < K; k0 += 32) {
#pragma unroll
        for (int p = 0; p < 2; p++) {
            int row = srow0 + p * 64;
            int gm = tm + row; if (gm >= M) gm = M - 1;
            if constexpr (MODE == 0) {
                const float* a = (const float*)Aptr + (size_t)gm * K + k0 + scol;
                float4 v0 = *(const float4*)a;
                float4 v1 = *(const float4*)(a + 4);
                bf16x8 o;
                o[0] = f2bf(v0.x); o[1] = f2bf(v0.y); o[2] = f2bf(v0.z); o[3] = f2bf(v0.w);
                o[4] = f2bf(v1.x); o[5] = f2bf(v1.y); o[6] = f2bf(v1.z); o[7] = f2bf(v1.w);
                *(bf16x8*)&Asl[row][scol] = o;
            } else {
                const short* a = (const short*)Aptr + (size_t)gm * K + k0 + scol;
                *(int4*)&Asl[row][scol] = *(const int4*)a;
            }
            const short* bsrc = Bw + (size_t)(tn + row) * K + k0 + scol;
            *(int4*)&Bsl[row][scol] = *(const int4*)bsrc;
        }
        __syncthreads();

        bf16x8 af[4], bfr[4];
#pragma unroll
        for (int i = 0; i < 4; i++) af[i]  = *(const bf16x8*)&Asl[wr + i * 16 + li][lg * 8];
#pragma unroll
        for (int j = 0; j < 4; j++) bfr[j] = *(const bf16x8*)&Bsl[wc + j * 16 + li][lg * 8];
#pragma unroll
        for (int i = 0; i < 4; i++)
#pragma unroll
            for (int j = 0; j < 4; j++)
                acc[i][j] = __builtin_amdgcn_mfma_f32_16x16x32_bf16(af[i], bfr[j], acc[i][j], 0, 0, 0);
        __syncthreads();
    }

    // epilogue
#pragma unroll
    for (int i = 0; i < 4; i++) {
#pragma unroll
        for (int j = 0; j < 4; j++) {
            int c = tn + wc + j * 16 + li;
#pragma unroll
            for (int r = 0; r < 4; r++) {
                int m = tm + wr + i * 16 + lg * 4 + r;
                if (m >= M) continue;
                float v = acc[i][j][r];
                if constexpr (MODE == 0) {
                    int which = c / EMB;
                    int e     = c % EMB;
                    const float* bb = (which == 0) ? b0 : ((which == 1) ? b1 : b2);
                    v += bb[e];
                    int b = m / NTOK, n = m % NTOK;
                    int h = e / HD, d = e % HD;
                    size_t off = ((((size_t)which * BATCH + b) * NHEAD + h) * NTOK + n) * HD + d;
                    ((short*)Outp)[off] = f2bf(v);
                } else {
                    v += b0[c];
                    ((float*)Outp)[(size_t)m * Ncols + c] = v;
                }
            }
        }
    }
}

// ---------------------------------------------------------------- flash attention
// grid: BATCH * NHEAD * NQT blocks, 256 threads (4 waves, 16 q-rows each)
__global__ __launch_bounds__(256) void attn_kernel(
    const short* __restrict__ qkv, const float* __restrict__ biasx,
    short* __restrict__ aout)
{
    __shared__ __align__(16) short Ksl[64][72];
    __shared__ __align__(16) short Vts[64][72];   // transposed: [d][key]
    __shared__ __align__(16) short Psl[4][16][72];

    const int bi = blockIdx.x;
    const int qt = bi % NQT;
    const int h  = (bi / NQT) % NHEAD;
    const int b  = bi / (NQT * NHEAD);
    const int t    = threadIdx.x;
    const int lane = t & 63;
    const int w    = t >> 6;
    const int lg   = lane >> 4;
    const int li   = lane & 15;
    const int qbase = qt * 64;

    const short* qp = qkv + (((size_t)(0 * BATCH + b) * NHEAD + h) * NTOK) * HD;
    const short* kp = qkv + (((size_t)(1 * BATCH + b) * NHEAD + h) * NTOK) * HD;
    const short* vp = qkv + (((size_t)(2 * BATCH + b) * NHEAD + h) * NTOK) * HD;

    // Q fragments for this wave's 16 rows (kept in registers for all KV tiles)
    bf16x8 qf[2];
    {
        int qrow = qbase + w * 16 + li; if (qrow >= NTOK) qrow = NTOK - 1;
        qf[0] = *(const bf16x8*)(qp + (size_t)qrow * HD + 0 + lg * 8);
        qf[1] = *(const bf16x8*)(qp + (size_t)qrow * HD + 32 + lg * 8);
    }

    float mrun[4], lrun[4];
    f32x4 oacc[4];
#pragma unroll
    for (int r = 0; r < 4; r++) { mrun[r] = -1e30f; lrun[r] = 0.f; }
#pragma unroll
    for (int d = 0; d < 4; d++) oacc[d] = (f32x4){0.f, 0.f, 0.f, 0.f};

    for (int kt = 0; kt < NKT; kt++) {
        // stage K tile [64 keys][64 d]
#pragma unroll
        for (int p = 0; p < 2; p++) {
            int c = t + p * 256;
            int kr = c >> 3, d0 = (c & 7) * 8;
            int key = kt * 64 + kr; if (key >= NTOK) key = NTOK - 1;
            *(int4*)&Ksl[kr][d0] = *(const int4*)(kp + (size_t)key * HD + d0);
        }
        // stage V transposed: Vts[d][key_local]
        {
            int d   = t >> 2;
            int krb = (t & 3) * 16;
            short tmp[16];
#pragma unroll
            for (int q = 0; q < 16; q++) {
                int key = kt * 64 + krb + q; if (key >= NTOK) key = NTOK - 1;
                tmp[q] = vp[(size_t)key * HD + d];
            }
            *(int4*)&Vts[d][krb]     = *(int4*)&tmp[0];
            *(int4*)&Vts[d][krb + 8] = *(int4*)&tmp[8];
        }
        __syncthreads();

        // S = Q K^T  (per wave: rows w*16..+15, cols 0..63 of this KV tile)
        float pv[4][4];   // [j (col frag)][r]
#pragma unroll
        for (int j = 0; j < 4; j++) {
            bf16x8 bk0 = *(const bf16x8*)&Ksl[j * 16 + li][lg * 8];
            bf16x8 bk1 = *(const bf16x8*)&Ksl[j * 16 + li][32 + lg * 8];
            f32x4 s = (f32x4){0.f, 0.f, 0.f, 0.f};
            s = __builtin_amdgcn_mfma_f32_16x16x32_bf16(qf[0], bk0, s, 0, 0, 0);
            s = __builtin_amdgcn_mfma_f32_16x16x32_bf16(qf[1], bk1, s, 0, 0, 0);
#pragma unroll
            for (int r = 0; r < 4; r++) {
                int q  = qbase + w * 16 + lg * 4 + r;
                int kc = kt * 64 + j * 16 + li;
                float v = s[r] * 0.125f;
                if (kc >= NTOK || q >= NTOK) v = -1e30f;
                else if (q >= 1 && kc >= 1)
                    v += biasx[((size_t)h * NGRID + (q - 1)) * NGRID + (kc - 1)];
                pv[j][r] = v;
            }
        }

        // online softmax per row (row lives in the 16-lane li-group)
#pragma unroll
        for (int r = 0; r < 4; r++) {
            float mt = fmaxf(fmaxf(pv[0][r], pv[1][r]), fmaxf(pv[2][r], pv[3][r]));
#pragma unroll
            for (int mk = 1; mk < 16; mk <<= 1) mt = fmaxf(mt, __shfl_xor(mt, mk, 64));
            float nm  = fmaxf(mrun[r], mt);
            float fac = __expf(mrun[r] - nm);
            float rs  = 0.f;
#pragma unroll
            for (int j = 0; j < 4; j++) {
                float p = __expf(pv[j][r] - nm);
                pv[j][r] = p;
                rs += p;
            }
#pragma unroll
            for (int mk = 1; mk < 16; mk <<= 1) rs += __shfl_xor(rs, mk, 64);
            lrun[r] = lrun[r] * fac + rs;
            mrun[r] = nm;
#pragma unroll
            for (int d = 0; d < 4; d++) oacc[d][r] *= fac;
        }

        // P -> bf16 -> per-wave LDS (C-layout -> A-layout transpose via LDS)
#pragma unroll
        for (int j = 0; j < 4; j++)
#pragma unroll
            for (int r = 0; r < 4; r++)
                Psl[w][lg * 4 + r][j * 16 + li] = f2bf(pv[j][r]);
        __syncthreads();

        // O += P @ V
#pragma unroll
        for (int dd = 0; dd < 4; dd++) {
#pragma unroll
            for (int kk = 0; kk < 2; kk++) {
                bf16x8 pa = *(const bf16x8*)&Psl[w][li][kk * 32 + lg * 8];
                bf16x8 bv = *(const bf16x8*)&Vts[dd * 16 + li][kk * 32 + lg * 8];
                oacc[dd] = __builtin_amdgcn_mfma_f32_16x16x32_bf16(pa, bv, oacc[dd], 0, 0, 0);
            }
        }
        __syncthreads();
    }

    // finalize: O /= l, store bf16 to [b][q][h*64+d]
#pragma unroll
    for (int dd = 0; dd < 4; dd++) {
#pragma unroll
        for (int r = 0; r < 4; r++) {
            int q = qbase + w * 16 + lg * 4 + r;
            if (q >= NTOK) continue;
            float v = oacc[dd][r] / lrun[r];
            aout[((size_t)b * NTOK + q) * EMB + h * HD + dd * 16 + li] = f2bf(v);
        }
    }
}

// ---------------------------------------------------------------- launch
extern "C" void kernel_launch(void* const* d_in, const int* in_sizes, int n_in,
                              void* d_out, int out_size, void* d_ws, size_t ws_size,
                              hipStream_t stream) {
    (void)in_sizes; (void)n_in; (void)out_size; (void)ws_size;
    const float* x   = (const float*)d_in[0];
    const float* Wq  = (const float*)d_in[1];
    const float* bq  = (const float*)d_in[2];
    const float* Wk  = (const float*)d_in[3];
    const float* bk  = (const float*)d_in[4];
    const float* Wv  = (const float*)d_in[5];
    const float* bv  = (const float*)d_in[6];
    const float* Wp  = (const float*)d_in[7];
    const float* bp  = (const float*)d_in[8];
    const float* rel = (const float*)d_in[9];

    // workspace carve-up (bf16 regions first, all 16B aligned)
    short* Wb   = (short*)d_ws;                         // [2304][768] bf16 (Wq|Wk|Wv)
    short* Wpb  = Wb + (size_t)3 * EMB * EMB;           // [768][768] bf16
    short* qkv  = Wpb + (size_t)EMB * EMB;              // [3][B][H][NTOK][HD] bf16
    short* aout = qkv + (size_t)3 * BATCH * NHEAD * NTOK * HD;  // [MROWS][768] bf16
    float* bexp = (float*)(aout + (size_t)MROWS * EMB); // [H][576][576] f32

    const int WN = EMB * EMB;  // 589824
    cast_f32_bf16<<<576, 256, 0, stream>>>(Wq, Wb, WN);
    cast_f32_bf16<<<576, 256, 0, stream>>>(Wk, Wb + WN, WN);
    cast_f32_bf16<<<576, 256, 0, stream>>>(Wv, Wb + 2 * WN, WN);
    cast_f32_bf16<<<576, 256, 0, stream>>>(Wp, Wpb, WN);
    bias_expand<<<NGRID, NGRID, 0, stream>>>(rel, bexp);

    gemm_bt<0><<<dim3(18, 145), 256, 0, stream>>>(x, Wb, bq, bk, bv, qkv, MROWS, 3 * EMB, EMB);
    attn_kernel<<<BATCH * NHEAD * NQT, 256, 0, stream>>>(qkv, bexp, aout);
    gemm_bt<1><<<dim3(6, 145), 256, 0, stream>>>(aout, Wpb, bp, bp, bp, d_out, MROWS, EMB, EMB);
}

// Round 2
// 410.768 us; speedup vs baseline: 1.2763x; 1.2763x over previous
//
#include <hip/hip_runtime.h>
#include <stdint.h>

#define HGT   24
#define WID   24
#define NHEAD 12
#define EMB   768
#define HD    64
#define NGRID 576
#define NTOK  577
#define NPAD  640              // padded token dim (10 tiles of 64)
#define BATCH 32
#define MROWS (BATCH * NTOK)   // 18464
#define NQT   10
#define NKT   10

typedef __attribute__((ext_vector_type(8))) short bf16x8;
typedef __attribute__((ext_vector_type(4))) float f32x4;

__device__ __forceinline__ short f2bf(float f) {
    union { float f; unsigned u; } c; c.f = f;
    unsigned r = (c.u + 0x7FFFu + ((c.u >> 16) & 1u)) >> 16;
    return (short)(r & 0xFFFFu);
}

// ---------------------------------------------------------------- cast f32->bf16
__global__ void cast_f32_bf16(const float* __restrict__ src, short* __restrict__ dst, int n) {
    int i = (blockIdx.x * blockDim.x + threadIdx.x) * 4;
    int stride = gridDim.x * blockDim.x * 4;
    for (int j = i; j < n; j += stride) {
        float4 v = *(const float4*)(src + j);
        short4 o;
        o.x = f2bf(v.x); o.y = f2bf(v.y); o.z = f2bf(v.z); o.w = f2bf(v.w);
        *(short4*)(dst + j) = o;
    }
}

// ---------------------------------------------------------------- padded bias table [H][640][640]
// q==0 / k==0 (CLS) -> 0 ; k>=577 -> -1e30 (masks pad keys) ; q>=577 rows -> 0 (discarded)
__global__ void bias_expand(const float* __restrict__ rel, float* __restrict__ be) {
    int q = blockIdx.x;     // 0..639
    int k = threadIdx.x;    // 0..639
    float v[NHEAD];
    if (k >= NTOK) {
#pragma unroll
        for (int h = 0; h < NHEAD; h++) v[h] = -1e30f;
    } else if (q == 0 || q >= NTOK || k == 0) {
#pragma unroll
        for (int h = 0; h < NHEAD; h++) v[h] = 0.f;
    } else {
        int i = q - 1, j = k - 1;
        int idx = ((i / WID) - (j / WID) + HGT - 1) * (2 * WID - 1)
                + ((i % WID) - (j % WID) + WID - 1);
        const float* rp = rel + (size_t)idx * NHEAD;
#pragma unroll
        for (int h = 0; h < NHEAD; h++) v[h] = rp[h];
    }
#pragma unroll
    for (int h = 0; h < NHEAD; h++)
        be[((size_t)h * NPAD + q) * NPAD + k] = v[h];
}

// ---------------------------------------------------------------- V transpose: vt[b][h][d][key(640)] = v[b][h][key][d]
__global__ __launch_bounds__(256) void transpose_v(const short* __restrict__ v, short* __restrict__ vt) {
    __shared__ __align__(16) short T[64][72];
    int bi = blockIdx.x;
    int kt = bi % NKT;
    int h  = (bi / NKT) % NHEAD;
    int b  = bi / (NKT * NHEAD);
    int t  = threadIdx.x;

    const short* vp = v + ((size_t)b * NHEAD + h) * NTOK * HD;
    int r  = t >> 2, cb = (t & 3) * 16;
    int key = kt * 64 + r; if (key >= NTOK) key = NTOK - 1;
    *(int4*)&T[r][cb]     = *(const int4*)(vp + (size_t)key * HD + cb);
    *(int4*)&T[r][cb + 8] = *(const int4*)(vp + (size_t)key * HD + cb + 8);
    __syncthreads();

    int d = t >> 2, kb = (t & 3) * 16;
    short tmp[16];
#pragma unroll
    for (int s = 0; s < 16; s++) tmp[s] = T[kb + s][d];
    short* dst = vt + (((size_t)b * NHEAD + h) * HD + d) * NPAD + kt * 64 + kb;
    *(int4*)&dst[0] = *(int4*)&tmp[0];
    *(int4*)&dst[8] = *(int4*)&tmp[8];
}

// ---------------------------------------------------------------- GEMM  C = A @ B^T (+bias)
template <int MODE>
__global__ __launch_bounds__(256) void gemm_bt(
    const void* __restrict__ Aptr, const short* __restrict__ Bw,
    const float* __restrict__ b0, const float* __restrict__ b1, const float* __restrict__ b2,
    void* __restrict__ Outp, int M, int Ncols, int K)
{
    __shared__ __align__(16) short Asl[128][40];
    __shared__ __align__(16) short Bsl[128][40];

    const int t    = threadIdx.x;
    const int lane = t & 63;
    const int w    = t >> 6;
    const int wr   = (w >> 1) * 64;
    const int wc   = (w & 1) * 64;
    const int lg   = lane >> 4;
    const int li   = lane & 15;
    const int tm   = blockIdx.y * 128;
    const int tn   = blockIdx.x * 128;

    f32x4 acc[4][4];
#pragma unroll
    for (int i = 0; i < 4; i++)
#pragma unroll
        for (int j = 0; j < 4; j++) acc[i][j] = (f32x4){0.f, 0.f, 0.f, 0.f};

    const int srow0 = t >> 2;
    const int scol  = (t & 3) * 8;

    for (int k0 = 0; k0 < K; k0 += 32) {
#pragma unroll
        for (int p = 0; p < 2; p++) {
            int row = srow0 + p * 64;
            int gm = tm + row; if (gm >= M) gm = M - 1;
            if constexpr (MODE == 0) {
                const float* a = (const float*)Aptr + (size_t)gm * K + k0 + scol;
                float4 v0 = *(const float4*)a;
                float4 v1 = *(const float4*)(a + 4);
                bf16x8 o;
                o[0] = f2bf(v0.x); o[1] = f2bf(v0.y); o[2] = f2bf(v0.z); o[3] = f2bf(v0.w);
                o[4] = f2bf(v1.x); o[5] = f2bf(v1.y); o[6] = f2bf(v1.z); o[7] = f2bf(v1.w);
                *(bf16x8*)&Asl[row][scol] = o;
            } else {
                const short* a = (const short*)Aptr + (size_t)gm * K + k0 + scol;
                *(int4*)&Asl[row][scol] = *(const int4*)a;
            }
            const short* bsrc = Bw + (size_t)(tn + row) * K + k0 + scol;
            *(int4*)&Bsl[row][scol] = *(const int4*)bsrc;
        }
        __syncthreads();

        bf16x8 af[4], bfr[4];
#pragma unroll
        for (int i = 0; i < 4; i++) af[i]  = *(const bf16x8*)&Asl[wr + i * 16 + li][lg * 8];
#pragma unroll
        for (int j = 0; j < 4; j++) bfr[j] = *(const bf16x8*)&Bsl[wc + j * 16 + li][lg * 8];
#pragma unroll
        for (int i = 0; i < 4; i++)
#pragma unroll
            for (int j = 0; j < 4; j++)
                acc[i][j] = __builtin_amdgcn_mfma_f32_16x16x32_bf16(af[i], bfr[j], acc[i][j], 0, 0, 0);
        __syncthreads();
    }

#pragma unroll
    for (int i = 0; i < 4; i++) {
#pragma unroll
        for (int j = 0; j < 4; j++) {
            int c = tn + wc + j * 16 + li;
#pragma unroll
            for (int r = 0; r < 4; r++) {
                int m = tm + wr + i * 16 + lg * 4 + r;
                if (m >= M) continue;
                float v = acc[i][j][r];
                if constexpr (MODE == 0) {
                    int which = c / EMB;
                    int e     = c % EMB;
                    const float* bb = (which == 0) ? b0 : ((which == 1) ? b1 : b2);
                    v += bb[e];
                    int b = m / NTOK, n = m % NTOK;
                    int h = e / HD, d = e % HD;
                    size_t off = ((((size_t)which * BATCH + b) * NHEAD + h) * NTOK + n) * HD + d;
                    ((short*)Outp)[off] = f2bf(v);
                } else {
                    v += b0[c];
                    ((float*)Outp)[(size_t)m * Ncols + c] = v;
                }
            }
        }
    }
}

// ---------------------------------------------------------------- flash attention
__global__ __launch_bounds__(256) void attn_kernel(
    const short* __restrict__ qkv, const short* __restrict__ vt,
    const float* __restrict__ biasx, short* __restrict__ aout)
{
    __shared__ __align__(16) short Ksl[64][72];
    __shared__ __align__(16) short Vsl[64][72];   // [d][key_local] (from pre-transposed vt)
    __shared__ __align__(16) short Psl[4][16][72];

    const int bi = blockIdx.x;
    const int qt = bi % NQT;
    const int h  = (bi / NQT) % NHEAD;
    const int b  = bi / (NQT * NHEAD);
    const int t    = threadIdx.x;
    const int lane = t & 63;
    const int w    = t >> 6;
    const int lg   = lane >> 4;
    const int li   = lane & 15;
    const int qbase = qt * 64;

    const short* qp  = qkv + ((size_t)b * NHEAD + h) * NTOK * HD;
    const short* kp  = qkv + ((size_t)(BATCH + b) * NHEAD + h) * NTOK * HD;
    const short* vtp = vt + ((size_t)b * NHEAD + h) * (size_t)HD * NPAD;
    const float* brow = biasx + ((size_t)h * NPAD + qbase + w * 16 + lg * 4) * NPAD + li;

    bf16x8 qf[2];
    {
        int qrow = qbase + w * 16 + li; if (qrow >= NTOK) qrow = NTOK - 1;
        qf[0] = *(const bf16x8*)(qp + (size_t)qrow * HD + lg * 8);
        qf[1] = *(const bf16x8*)(qp + (size_t)qrow * HD + 32 + lg * 8);
    }

    float mrun[4], lrun[4];
    f32x4 oacc[4];
#pragma unroll
    for (int r = 0; r < 4; r++) { mrun[r] = -1e30f; lrun[r] = 0.f; }
#pragma unroll
    for (int d = 0; d < 4; d++) oacc[d] = (f32x4){0.f, 0.f, 0.f, 0.f};

    const int skr = t >> 3, sd0 = (t & 7) * 8;    // K staging coords
    const int vd  = t >> 2, vk  = (t & 3) * 16;   // V staging coords

    for (int kt = 0; kt < NKT; kt++) {
        // stage K tile [64 keys][64 d] (coalesced)
#pragma unroll
        for (int p = 0; p < 2; p++) {
            int kr = skr + p * 32;
            int key = kt * 64 + kr; if (key >= NTOK) key = NTOK - 1;
            *(int4*)&Ksl[kr][sd0] = *(const int4*)(kp + (size_t)key * HD + sd0);
        }
        // stage V^T tile [64 d][64 keys] (coalesced from vt)
        *(int4*)&Vsl[vd][vk]     = *(const int4*)(vtp + (size_t)vd * NPAD + kt * 64 + vk);
        *(int4*)&Vsl[vd][vk + 8] = *(const int4*)(vtp + (size_t)vd * NPAD + kt * 64 + vk + 8);
        __syncthreads();

        // S = Q K^T + bias (branch-free: masking baked into padded table)
        const float* bp2 = brow + kt * 64;
        float pv[4][4];
#pragma unroll
        for (int j = 0; j < 4; j++) {
            bf16x8 bk0 = *(const bf16x8*)&Ksl[j * 16 + li][lg * 8];
            bf16x8 bk1 = *(const bf16x8*)&Ksl[j * 16 + li][32 + lg * 8];
            f32x4 s = (f32x4){0.f, 0.f, 0.f, 0.f};
            s = __builtin_amdgcn_mfma_f32_16x16x32_bf16(qf[0], bk0, s, 0, 0, 0);
            s = __builtin_amdgcn_mfma_f32_16x16x32_bf16(qf[1], bk1, s, 0, 0, 0);
#pragma unroll
            for (int r = 0; r < 4; r++)
                pv[j][r] = fmaf(s[r], 0.125f, bp2[r * NPAD + j * 16]);
        }

        // online softmax per row
#pragma unroll
        for (int r = 0; r < 4; r++) {
            float mt = fmaxf(fmaxf(pv[0][r], pv[1][r]), fmaxf(pv[2][r], pv[3][r]));
#pragma unroll
            for (int mk = 1; mk < 16; mk <<= 1) mt = fmaxf(mt, __shfl_xor(mt, mk, 64));
            float nm  = fmaxf(mrun[r], mt);
            float fac = __expf(mrun[r] - nm);
            float rs  = 0.f;
#pragma unroll
            for (int j = 0; j < 4; j++) {
                float p = __expf(pv[j][r] - nm);
                pv[j][r] = p;
                rs += p;
            }
#pragma unroll
            for (int mk = 1; mk < 16; mk <<= 1) rs += __shfl_xor(rs, mk, 64);
            lrun[r] = lrun[r] * fac + rs;
            mrun[r] = nm;
#pragma unroll
            for (int d = 0; d < 4; d++) oacc[d][r] *= fac;
        }

        // P -> bf16 -> per-wave LDS (wave-private: no barrier needed)
#pragma unroll
        for (int j = 0; j < 4; j++)
#pragma unroll
            for (int r = 0; r < 4; r++)
                Psl[w][lg * 4 + r][j * 16 + li] = f2bf(pv[j][r]);

        // O += P @ V
#pragma unroll
        for (int dd = 0; dd < 4; dd++) {
#pragma unroll
            for (int kk = 0; kk < 2; kk++) {
                bf16x8 pa = *(const bf16x8*)&Psl[w][li][kk * 32 + lg * 8];
                bf16x8 bv = *(const bf16x8*)&Vsl[dd * 16 + li][kk * 32 + lg * 8];
                oacc[dd] = __builtin_amdgcn_mfma_f32_16x16x32_bf16(pa, bv, oacc[dd], 0, 0, 0);
            }
        }
        __syncthreads();
    }

#pragma unroll
    for (int dd = 0; dd < 4; dd++) {
#pragma unroll
        for (int r = 0; r < 4; r++) {
            int q = qbase + w * 16 + lg * 4 + r;
            if (q >= NTOK) continue;
            float v = oacc[dd][r] / lrun[r];
            aout[((size_t)b * NTOK + q) * EMB + h * HD + dd * 16 + li] = f2bf(v);
        }
    }
}

// ---------------------------------------------------------------- launch
extern "C" void kernel_launch(void* const* d_in, const int* in_sizes, int n_in,
                              void* d_out, int out_size, void* d_ws, size_t ws_size,
                              hipStream_t stream) {
    (void)in_sizes; (void)n_in; (void)out_size; (void)ws_size;
    const float* x   = (const float*)d_in[0];
    const float* Wq  = (const float*)d_in[1];
    const float* bq  = (const float*)d_in[2];
    const float* Wk  = (const float*)d_in[3];
    const float* bk  = (const float*)d_in[4];
    const float* Wv  = (const float*)d_in[5];
    const float* bv  = (const float*)d_in[6];
    const float* Wp  = (const float*)d_in[7];
    const float* bp  = (const float*)d_in[8];
    const float* rel = (const float*)d_in[9];

    const size_t WN = (size_t)EMB * EMB;                    // 589824
    short* Wb   = (short*)d_ws;                             // [2304][768] bf16
    short* Wpb  = Wb + 3 * WN;                              // [768][768] bf16
    short* qkv  = Wpb + WN;                                 // [3][B][H][NTOK][HD] bf16
    short* aout = qkv + (size_t)3 * BATCH * NHEAD * NTOK * HD;
    short* vtb  = aout + (size_t)MROWS * EMB;               // [B][H][HD][640] bf16
    float* bexp = (float*)(vtb + (size_t)BATCH * NHEAD * HD * NPAD); // [H][640][640] f32

    cast_f32_bf16<<<576, 256, 0, stream>>>(Wq, Wb, (int)WN);
    cast_f32_bf16<<<576, 256, 0, stream>>>(Wk, Wb + WN, (int)WN);
    cast_f32_bf16<<<576, 256, 0, stream>>>(Wv, Wb + 2 * WN, (int)WN);
    cast_f32_bf16<<<576, 256, 0, stream>>>(Wp, Wpb, (int)WN);
    bias_expand<<<NPAD, NPAD, 0, stream>>>(rel, bexp);

    gemm_bt<0><<<dim3(18, 145), 256, 0, stream>>>(x, Wb, bq, bk, bv, qkv, MROWS, 3 * EMB, EMB);
    transpose_v<<<BATCH * NHEAD * NKT, 256, 0, stream>>>(
        qkv + (size_t)2 * BATCH * NHEAD * NTOK * HD, vtb);
    attn_kernel<<<BATCH * NHEAD * NQT, 256, 0, stream>>>(qkv, vtb, bexp, aout);
    gemm_bt<1><<<dim3(6, 145), 256, 0, stream>>>(aout, Wpb, bp, bp, bp, d_out, MROWS, EMB, EMB);
}

// Round 3
// 378.048 us; speedup vs baseline: 1.3868x; 1.0865x over previous
//
#include <hip/hip_runtime.h>
#include <stdint.h>

#define HGT   24
#define WID   24
#define NHEAD 12
#define EMB   768
#define HD    64
#define NGRID 576
#define NTOK  577
#define NPAD  640              // padded token dim (10 tiles of 64)
#define BATCH 32
#define MROWS (BATCH * NTOK)   // 18464
#define NQT   10
#define NKT   10

typedef __attribute__((ext_vector_type(8))) short bf16x8;
typedef __attribute__((ext_vector_type(4))) float f32x4;

__device__ __forceinline__ short f2bf(float f) {
    union { float f; unsigned u; } c; c.f = f;
    unsigned r = (c.u + 0x7FFFu + ((c.u >> 16) & 1u)) >> 16;
    return (short)(r & 0xFFFFu);
}

// async global->LDS, 16B per lane; LDS dest = wave-uniform base + lane*16
__device__ __forceinline__ void gload16(void* lds, const void* g) {
    __builtin_amdgcn_global_load_lds(
        (const __attribute__((address_space(1))) void*)g,
        (__attribute__((address_space(3))) void*)lds, 16, 0, 0);
}

// ---------------------------------------------------------------- cast f32->bf16
__global__ void cast_f32_bf16(const float* __restrict__ src, short* __restrict__ dst, int n) {
    int i = (blockIdx.x * blockDim.x + threadIdx.x) * 4;
    int stride = gridDim.x * blockDim.x * 4;
    for (int j = i; j < n; j += stride) {
        float4 v = *(const float4*)(src + j);
        short4 o;
        o.x = f2bf(v.x); o.y = f2bf(v.y); o.z = f2bf(v.z); o.w = f2bf(v.w);
        *(short4*)(dst + j) = o;
    }
}

// ---------------------------------------------------------------- padded bias table [H][640][640]
__global__ void bias_expand(const float* __restrict__ rel, float* __restrict__ be) {
    int q = blockIdx.x;     // 0..639
    int k = threadIdx.x;    // 0..639
    float v[NHEAD];
    if (k >= NTOK) {
#pragma unroll
        for (int h = 0; h < NHEAD; h++) v[h] = -1e30f;
    } else if (q == 0 || q >= NTOK || k == 0) {
#pragma unroll
        for (int h = 0; h < NHEAD; h++) v[h] = 0.f;
    } else {
        int i = q - 1, j = k - 1;
        int idx = ((i / WID) - (j / WID) + HGT - 1) * (2 * WID - 1)
                + ((i % WID) - (j % WID) + WID - 1);
        const float* rp = rel + (size_t)idx * NHEAD;
#pragma unroll
        for (int h = 0; h < NHEAD; h++) v[h] = rp[h];
    }
#pragma unroll
    for (int h = 0; h < NHEAD; h++)
        be[((size_t)h * NPAD + q) * NPAD + k] = v[h];
}

// ---------------------------------------------------------------- V transpose: vt[b][h][d][key(640)]
__global__ __launch_bounds__(256) void transpose_v(const short* __restrict__ v, short* __restrict__ vt) {
    __shared__ __align__(16) short T[64][72];
    int bi = blockIdx.x;
    int kt = bi % NKT;
    int h  = (bi / NKT) % NHEAD;
    int b  = bi / (NKT * NHEAD);
    int t  = threadIdx.x;

    const short* vp = v + ((size_t)b * NHEAD + h) * NTOK * HD;
    int r  = t >> 2, cb = (t & 3) * 16;
    int key = kt * 64 + r; if (key >= NTOK) key = NTOK - 1;
    *(int4*)&T[r][cb]     = *(const int4*)(vp + (size_t)key * HD + cb);
    *(int4*)&T[r][cb + 8] = *(const int4*)(vp + (size_t)key * HD + cb + 8);
    __syncthreads();

    int d = t >> 2, kb = (t & 3) * 16;
    short tmp[16];
#pragma unroll
    for (int s = 0; s < 16; s++) tmp[s] = T[kb + s][d];
    short* dst = vt + (((size_t)b * NHEAD + h) * HD + d) * NPAD + kt * 64 + kb;
    *(int4*)&dst[0] = *(int4*)&tmp[0];
    *(int4*)&dst[8] = *(int4*)&tmp[8];
}

// ---------------------------------------------------------------- GEMM  C = A @ B^T (+bias)
// A: [M][K] bf16 ; Bw: [Ncols][K] bf16
// MODE 0: Ncols=2304, scatter bf16 into qkv[3][B][H][NTOK][HD], biases b0/b1/b2
// MODE 1: Ncols=768, f32 out + b0
template <int MODE>
__global__ __launch_bounds__(256) void gemm_bt(
    const short* __restrict__ A, const short* __restrict__ Bw,
    const float* __restrict__ b0, const float* __restrict__ b1, const float* __restrict__ b2,
    void* __restrict__ Outp, int M, int Ncols, int K)
{
    // linear layout (global_load_lds requirement); swizzle via pre-swizzled source
    __shared__ __align__(16) short Asl[128][64];
    __shared__ __align__(16) short Bsl[128][64];

    const int t    = threadIdx.x;
    const int lane = t & 63;
    const int w    = t >> 6;
    const int wr   = (w >> 1) * 64;
    const int wc   = (w & 1) * 64;
    const int lg   = lane >> 4;
    const int li   = lane & 15;
    const int xh   = li & 7;
    const int tm   = blockIdx.y * 128;
    const int tn   = blockIdx.x * 128;

    // staging geometry: issue p covers rows [p*32, p*32+32); wave w rows p*32+w*8..+7
    // lane l: row = p*32 + w*8 + (l>>3); phys chunk = l&7 holds logical chunk (l&7)^(row&7)
    const int srow = w * 8 + (lane >> 3);
    const int cofs = (((lane & 7) ^ (lane >> 3)) * 8);   // shorts

    const short* ag[4];
    const short* bg[4];
#pragma unroll
    for (int p = 0; p < 4; p++) {
        int rm = tm + p * 32 + srow; if (rm >= M) rm = M - 1;
        ag[p] = A  + (size_t)rm * K + cofs;
        bg[p] = Bw + (size_t)(tn + p * 32 + srow) * K + cofs;
    }

    f32x4 acc[4][4];
#pragma unroll
    for (int i = 0; i < 4; i++)
#pragma unroll
        for (int j = 0; j < 4; j++) acc[i][j] = (f32x4){0.f, 0.f, 0.f, 0.f};

    for (int k0 = 0; k0 < K; k0 += 64) {
#pragma unroll
        for (int p = 0; p < 4; p++) {
            gload16(&Asl[p * 32 + w * 8][0], ag[p] + k0);
            gload16(&Bsl[p * 32 + w * 8][0], bg[p] + k0);
        }
        __syncthreads();   // drains vmcnt(0): tiles ready

#pragma unroll
        for (int kk = 0; kk < 2; kk++) {
            bf16x8 af[4], bfr[4];
#pragma unroll
            for (int i = 0; i < 4; i++)
                af[i]  = *(const bf16x8*)&Asl[wr + i * 16 + li][((kk * 4 + lg) ^ xh) * 8];
#pragma unroll
            for (int j = 0; j < 4; j++)
                bfr[j] = *(const bf16x8*)&Bsl[wc + j * 16 + li][((kk * 4 + lg) ^ xh) * 8];
#pragma unroll
            for (int i = 0; i < 4; i++)
#pragma unroll
                for (int j = 0; j < 4; j++)
                    acc[i][j] = __builtin_amdgcn_mfma_f32_16x16x32_bf16(af[i], bfr[j], acc[i][j], 0, 0, 0);
        }
        __syncthreads();   // protect LDS overwrite next step
    }

#pragma unroll
    for (int i = 0; i < 4; i++) {
#pragma unroll
        for (int j = 0; j < 4; j++) {
            int c = tn + wc + j * 16 + li;
#pragma unroll
            for (int r = 0; r < 4; r++) {
                int m = tm + wr + i * 16 + lg * 4 + r;
                if (m >= M) continue;
                float v = acc[i][j][r];
                if constexpr (MODE == 0) {
                    int which = c / EMB;
                    int e     = c % EMB;
                    const float* bb = (which == 0) ? b0 : ((which == 1) ? b1 : b2);
                    v += bb[e];
                    int b = m / NTOK, n = m % NTOK;
                    int h = e / HD, d = e % HD;
                    size_t off = ((((size_t)which * BATCH + b) * NHEAD + h) * NTOK + n) * HD + d;
                    ((short*)Outp)[off] = f2bf(v);
                } else {
                    v += b0[c];
                    ((float*)Outp)[(size_t)m * Ncols + c] = v;
                }
            }
        }
    }
}

// ---------------------------------------------------------------- flash attention
__global__ __launch_bounds__(256) void attn_kernel(
    const short* __restrict__ qkv, const short* __restrict__ vt,
    const float* __restrict__ biasx, short* __restrict__ aout)
{
    __shared__ __align__(16) short Ksl[64][64];
    __shared__ __align__(16) short Vsl[64][64];   // [d][key_local]
    __shared__ __align__(16) short Psl[4][16][72];

    const int bi = blockIdx.x;
    const int qt = bi % NQT;
    const int h  = (bi / NQT) % NHEAD;
    const int b  = bi / (NQT * NHEAD);
    const int t    = threadIdx.x;
    const int lane = t & 63;
    const int w    = t >> 6;
    const int lg   = lane >> 4;
    const int li   = lane & 15;
    const int xh   = li & 7;
    const int qbase = qt * 64;

    const short* qp  = qkv + ((size_t)b * NHEAD + h) * NTOK * HD;
    const short* kp  = qkv + ((size_t)(BATCH + b) * NHEAD + h) * NTOK * HD;
    const short* vtp = vt + ((size_t)b * NHEAD + h) * (size_t)HD * NPAD;
    const float* brow = biasx + ((size_t)h * NPAD + qbase + w * 16 + lg * 4) * NPAD + li;

    bf16x8 qf[2];
    {
        int qrow = qbase + w * 16 + li; if (qrow >= NTOK) qrow = NTOK - 1;
        qf[0] = *(const bf16x8*)(qp + (size_t)qrow * HD + lg * 8);
        qf[1] = *(const bf16x8*)(qp + (size_t)qrow * HD + 32 + lg * 8);
    }

    float mrun[4], lrun[4];
    f32x4 oacc[4];
#pragma unroll
    for (int r = 0; r < 4; r++) { mrun[r] = -1e30f; lrun[r] = 0.f; }
#pragma unroll
    for (int d = 0; d < 4; d++) oacc[d] = (f32x4){0.f, 0.f, 0.f, 0.f};

    const int srow = w * 8 + (lane >> 3);
    const int cofs = (((lane & 7) ^ (lane >> 3)) * 8);

    for (int kt = 0; kt < NKT; kt++) {
        // stage K + V^T tiles via global_load_lds (pre-swizzled source)
#pragma unroll
        for (int p = 0; p < 2; p++) {
            int key = kt * 64 + p * 32 + srow; if (key >= NTOK) key = NTOK - 1;
            gload16(&Ksl[p * 32 + w * 8][0], kp + (size_t)key * HD + cofs);
            gload16(&Vsl[p * 32 + w * 8][0], vtp + (size_t)(p * 32 + srow) * NPAD + kt * 64 + cofs);
        }
        __syncthreads();

        // S = Q K^T + bias (branch-free)
        const float* bp2 = brow + kt * 64;
        float pvv[4][4];
        __builtin_amdgcn_s_setprio(1);
#pragma unroll
        for (int j = 0; j < 4; j++) {
            bf16x8 bk0 = *(const bf16x8*)&Ksl[j * 16 + li][(lg ^ xh) * 8];
            bf16x8 bk1 = *(const bf16x8*)&Ksl[j * 16 + li][((4 + lg) ^ xh) * 8];
            f32x4 s = (f32x4){0.f, 0.f, 0.f, 0.f};
            s = __builtin_amdgcn_mfma_f32_16x16x32_bf16(qf[0], bk0, s, 0, 0, 0);
            s = __builtin_amdgcn_mfma_f32_16x16x32_bf16(qf[1], bk1, s, 0, 0, 0);
#pragma unroll
            for (int r = 0; r < 4; r++)
                pvv[j][r] = fmaf(s[r], 0.125f, bp2[r * NPAD + j * 16]);
        }
        __builtin_amdgcn_s_setprio(0);

        // online softmax per row
#pragma unroll
        for (int r = 0; r < 4; r++) {
            float mt = fmaxf(fmaxf(pvv[0][r], pvv[1][r]), fmaxf(pvv[2][r], pvv[3][r]));
#pragma unroll
            for (int mk = 1; mk < 16; mk <<= 1) mt = fmaxf(mt, __shfl_xor(mt, mk, 64));
            float nm  = fmaxf(mrun[r], mt);
            float fac = __expf(mrun[r] - nm);
            float rs  = 0.f;
#pragma unroll
            for (int j = 0; j < 4; j++) {
                float p = __expf(pvv[j][r] - nm);
                pvv[j][r] = p;
                rs += p;
            }
#pragma unroll
            for (int mk = 1; mk < 16; mk <<= 1) rs += __shfl_xor(rs, mk, 64);
            lrun[r] = lrun[r] * fac + rs;
            mrun[r] = nm;
#pragma unroll
            for (int d = 0; d < 4; d++) oacc[d][r] *= fac;
        }

        // P -> bf16 -> per-wave LDS (wave-private)
#pragma unroll
        for (int j = 0; j < 4; j++)
#pragma unroll
            for (int r = 0; r < 4; r++)
                Psl[w][lg * 4 + r][j * 16 + li] = f2bf(pvv[j][r]);

        // O += P @ V
        __builtin_amdgcn_s_setprio(1);
#pragma unroll
        for (int dd = 0; dd < 4; dd++) {
#pragma unroll
            for (int kk = 0; kk < 2; kk++) {
                bf16x8 pa = *(const bf16x8*)&Psl[w][li][kk * 32 + lg * 8];
                bf16x8 bv = *(const bf16x8*)&Vsl[dd * 16 + li][((kk * 4 + lg) ^ xh) * 8];
                oacc[dd] = __builtin_amdgcn_mfma_f32_16x16x32_bf16(pa, bv, oacc[dd], 0, 0, 0);
            }
        }
        __builtin_amdgcn_s_setprio(0);
        __syncthreads();
    }

#pragma unroll
    for (int dd = 0; dd < 4; dd++) {
#pragma unroll
        for (int r = 0; r < 4; r++) {
            int q = qbase + w * 16 + lg * 4 + r;
            if (q >= NTOK) continue;
            float v = oacc[dd][r] / lrun[r];
            aout[((size_t)b * NTOK + q) * EMB + h * HD + dd * 16 + li] = f2bf(v);
        }
    }
}

// ---------------------------------------------------------------- launch
extern "C" void kernel_launch(void* const* d_in, const int* in_sizes, int n_in,
                              void* d_out, int out_size, void* d_ws, size_t ws_size,
                              hipStream_t stream) {
    (void)in_sizes; (void)n_in; (void)out_size; (void)ws_size;
    const float* x   = (const float*)d_in[0];
    const float* Wq  = (const float*)d_in[1];
    const float* bq  = (const float*)d_in[2];
    const float* Wk  = (const float*)d_in[3];
    const float* bk  = (const float*)d_in[4];
    const float* Wv  = (const float*)d_in[5];
    const float* bv  = (const float*)d_in[6];
    const float* Wp  = (const float*)d_in[7];
    const float* bp  = (const float*)d_in[8];
    const float* rel = (const float*)d_in[9];

    const size_t WN = (size_t)EMB * EMB;                    // 589824
    short* Wb   = (short*)d_ws;                             // [2304][768] bf16
    short* Wpb  = Wb + 3 * WN;                              // [768][768] bf16
    short* qkv  = Wpb + WN;                                 // [3][B][H][NTOK][HD] bf16
    short* xb   = qkv + (size_t)3 * BATCH * NHEAD * NTOK * HD;  // [MROWS][768] bf16
    short* aout = xb;                                       // ALIAS: xb dead after gemm0
    short* vtb  = xb + (size_t)MROWS * EMB;                 // [B][H][HD][640] bf16
    float* bexp = (float*)(vtb + (size_t)BATCH * NHEAD * HD * NPAD); // [H][640][640] f32

    const int XN = MROWS * EMB;  // 14180352
    cast_f32_bf16<<<576, 256, 0, stream>>>(Wq, Wb, (int)WN);
    cast_f32_bf16<<<576, 256, 0, stream>>>(Wk, Wb + WN, (int)WN);
    cast_f32_bf16<<<576, 256, 0, stream>>>(Wv, Wb + 2 * WN, (int)WN);
    cast_f32_bf16<<<576, 256, 0, stream>>>(Wp, Wpb, (int)WN);
    cast_f32_bf16<<<13848, 256, 0, stream>>>(x, xb, XN);
    bias_expand<<<NPAD, NPAD, 0, stream>>>(rel, bexp);

    gemm_bt<0><<<dim3(18, 145), 256, 0, stream>>>(xb, Wb, bq, bk, bv, qkv, MROWS, 3 * EMB, EMB);
    transpose_v<<<BATCH * NHEAD * NKT, 256, 0, stream>>>(
        qkv + (size_t)2 * BATCH * NHEAD * NTOK * HD, vtb);
    attn_kernel<<<BATCH * NHEAD * NQT, 256, 0, stream>>>(qkv, vtb, bexp, aout);
    gemm_bt<1><<<dim3(6, 145), 256, 0, stream>>>(aout, Wpb, bp, bp, bp, d_out, MROWS, EMB, EMB);
}